// Round 3
// baseline (16642.741 us; speedup 1.0000x reference)
//
#include <hip/hip_runtime.h>
#include <math.h>

// ---------------------------------------------------------------------------
// Fused 16-layer LSTM pipeline (H=512, T=4096) + MLP head.
//
//  - 256 blocks = 16 layers x 16 blocks/layer, 512 thr, 1 block/CU.
//  - Weights fully register-resident: f,g gates fp32 (128 VGPR), i,o gates
//    f16 packed (64 VGPR) consumed via v_dot2_f32_f16. amdgpu_waves_per_eu(2,2)
//    pins the register budget to 256 so nothing spills (round-2 bug: compiler
//    chose 128 VGPR and spilled 192 floats -> 324 GB of scratch re-reads).
//  - Handshake: tagged 8B atoms {f32 h bits, tag=t+1} in per-layer rings.
//    Consumers poll the data word itself (1 RT) instead of flag->data (2 RT);
//    producers fire one sc1 store (no vmcnt-drain + flag store). Rings are
//    memset to 0 each launch (tag 0 invalid -> replay-safe).
//  - Per step: phase-A computes the x-half matvec (x_t was posted one link
//    ago -> ready) while sibling h_{t-1} tags are still in flight; phase-B
//    polls h and computes the h-half. 2 barriers/step.
//  - Backpressure: every-8-steps progress flags; producer requires next-layer
//    progress >= t-48 (ring has 64 slots) -- off critical path.
// ---------------------------------------------------------------------------

#define T_SEQ 4096
#define HDIM  512
#define NL    16
#define BPL   16
#define NTH   512
#define RING  64

typedef unsigned long long u64;
typedef _Float16 half2v __attribute__((ext_vector_type(2)));

struct Args {
  const float* x;
  const float* Wih[NL]; const float* Whh[NL];
  const float* bih[NL]; const float* bhh[NL];
  u64* ring;        // [NL][RING][HDIM] tagged h
  unsigned* prog;   // [NL*BPL] (+pad)
  float* sout;      // [T_SEQ][HDIM]
};

__device__ __forceinline__ u64 aloadU(const u64* p) {
  return __hip_atomic_load(p, __ATOMIC_RELAXED, __HIP_MEMORY_SCOPE_AGENT);
}
__device__ __forceinline__ void astoreU(u64* p, u64 v) {
  __hip_atomic_store(p, v, __ATOMIC_RELAXED, __HIP_MEMORY_SCOPE_AGENT);
}
__device__ __forceinline__ unsigned aloadu(const unsigned* p) {
  return __hip_atomic_load(p, __ATOMIC_RELAXED, __HIP_MEMORY_SCOPE_AGENT);
}
__device__ __forceinline__ float sigm(float x) { return 1.f / (1.f + __expf(-x)); }
__device__ __forceinline__ float tanhx(float x) {
  const float e = __expf(-2.f * fabsf(x));
  const float r = (1.f - e) / (1.f + e);
  return copysignf(r, x);
}

#if __has_builtin(__builtin_amdgcn_fdot2)
#define DOT2(w, v, acc) __builtin_amdgcn_fdot2((w), (v), (acc), false)
#else
__device__ __forceinline__ float DOT2(half2v w, half2v v, float acc) {
  return acc + (float)w.x * (float)v.x + (float)w.y * (float)v.y;
}
#endif

#define DOT4(acc, wv, vv)                                          \
  acc = fmaf((wv).x, (vv).x, acc); acc = fmaf((wv).y, (vv).y, acc); \
  acc = fmaf((wv).z, (vv).z, acc); acc = fmaf((wv).w, (vv).w, acc)

__attribute__((amdgpu_waves_per_eu(2, 2)))
__global__ void __launch_bounds__(NTH) lstm16_kernel(Args a)
{
  const int tid   = threadIdx.x;
  const int layer = blockIdx.x & 15;   // siblings {l, l+16, ...} share an XCD (i%8)
  const int b     = blockIdx.x >> 4;
  const int rq    = tid >> 5;          // 0..15: h-pair group
  const int cs    = tid & 31;          // 0..31: k-chunk (16x + 16h floats)
  const int kx    = cs * 16;
  const int Dstride = layer ? HDIM : 128;

  // LDS: v vectors only (~20.6 KB). Chunk stride 17 float4s / 3 uint4s keeps
  // the 32-lane b128 reads at the conflict-free minimum.
  __shared__ __align__(16) float    vx32[32 * 68];
  __shared__ __align__(16) float    vh32[32 * 68];
  __shared__ __align__(16) unsigned vx16[32 * 12];
  __shared__ __align__(16) unsigned vh16[32 * 12];
  __shared__ float hown[32];

  // ---- register-resident weights ----
  float4 wfx[2][4], wfh[2][4], wgx[2][4], wgh[2][4];   // f,g fp32: 128 VGPR
  half2v wix[2][8], wih2[2][8], wox[2][8], woh2[2][8]; // i,o f16:  64 VGPR
  float  bs[2][4];
  float  cst[2] = {0.f, 0.f};

  const bool xok = (kx + 16 <= Dstride);
  #pragma unroll
  for (int j = 0; j < 2; ++j) {
    const int hj = b * 32 + rq * 2 + j;
    #pragma unroll
    for (int q = 0; q < 4; ++q)
      bs[j][q] = a.bih[layer][q * HDIM + hj] + a.bhh[layer][q * HDIM + hj];
    const float* Wi = a.Wih[layer];
    const float* Wh = a.Whh[layer];
    const float4* pfx = (const float4*)(Wi + (size_t)(1 * HDIM + hj) * Dstride + kx);
    const float4* pgx = (const float4*)(Wi + (size_t)(2 * HDIM + hj) * Dstride + kx);
    const float4* pfh = (const float4*)(Wh + (size_t)(1 * HDIM + hj) * HDIM + kx);
    const float4* pgh = (const float4*)(Wh + (size_t)(2 * HDIM + hj) * HDIM + kx);
    #pragma unroll
    for (int m = 0; m < 4; ++m) {
      wfx[j][m] = xok ? pfx[m] : make_float4(0, 0, 0, 0);
      wgx[j][m] = xok ? pgx[m] : make_float4(0, 0, 0, 0);
      wfh[j][m] = pfh[m];
      wgh[j][m] = pgh[m];
    }
    const float2* pix = (const float2*)(Wi + (size_t)(0 * HDIM + hj) * Dstride + kx);
    const float2* pox = (const float2*)(Wi + (size_t)(3 * HDIM + hj) * Dstride + kx);
    const float2* pih = (const float2*)(Wh + (size_t)(0 * HDIM + hj) * HDIM + kx);
    const float2* poh = (const float2*)(Wh + (size_t)(3 * HDIM + hj) * HDIM + kx);
    #pragma unroll
    for (int p = 0; p < 8; ++p) {
      const float2 t0 = xok ? pix[p] : make_float2(0, 0);
      const float2 t1 = xok ? pox[p] : make_float2(0, 0);
      const float2 t2 = pih[p];
      const float2 t3 = poh[p];
      half2v w0; w0.x = (_Float16)t0.x; w0.y = (_Float16)t0.y; wix[j][p]  = w0;
      half2v w1; w1.x = (_Float16)t1.x; w1.y = (_Float16)t1.y; wox[j][p]  = w1;
      half2v w2; w2.x = (_Float16)t2.x; w2.y = (_Float16)t2.y; wih2[j][p] = w2;
      half2v w3; w3.x = (_Float16)t3.x; w3.y = (_Float16)t3.y; woh2[j][p] = w3;
    }
  }

  u64* ringOwn        = a.ring + (size_t)layer * RING * HDIM;
  const u64* ringPrev = a.ring + (size_t)(layer - 1) * RING * HDIM;
  const unsigned* progNext = a.prog + (layer + 1) * BPL;
  unsigned* myprog         = a.prog + layer * BPL + b;

  const int  bpidx = tid - 64;
  const bool isbp  = (layer < NL - 1) && (bpidx >= 0) && (bpidx < BPL);
  const int  i32   = (tid >> 4) * 68 + (tid & 15);
  const int  i16   = (tid >> 4) * 12 + ((tid & 15) >> 1);
  const int  ownlo = b * 32;

  for (int t = 0; t < T_SEQ; ++t) {
    const int slot = t & (RING - 1);

    // ---------------- phase A: x (ready ~1 link ago) ----------------
    float xv;
    bool okbp = !(isbp && ((t & 7) == 0));
    if (layer == 0) {
      xv = (tid < 128) ? a.x[(size_t)t * 128 + tid] : 0.f;
      if (!okbp) while ((int)aloadu(progNext + bpidx) < t - 48) {}
    } else {
      const u64* xw = ringPrev + (size_t)slot * HDIM + tid;
      u64 u = 0; bool ok = false;
      do {
        if (!ok)   { u = aloadU(xw); ok = ((unsigned)(u >> 32) == (unsigned)(t + 1)); }
        if (!okbp) { okbp = ((int)aloadu(progNext + bpidx) >= t - 48); }
      } while (!__all(ok & okbp));
      xv = __builtin_bit_cast(float, (unsigned)(u & 0xffffffffu));
    }
    vx32[i32] = xv;
    {
      const float nb = __shfl_down(xv, 1);
      if (!(tid & 1)) {
        half2v pk; pk.x = (_Float16)xv; pk.y = (_Float16)nb;
        vx16[i16] = __builtin_bit_cast(unsigned, pk);
      }
    }
    __syncthreads();   // B1

    float ai0 = 0, ai1 = 0, af0 = 0, af1 = 0, ag0 = 0, ag1 = 0, ao0 = 0, ao1 = 0;
    {
      const float4* v4 = (const float4*)vx32 + (size_t)cs * 17;
      #pragma unroll
      for (int m = 0; m < 4; ++m) {
        const float4 vv = v4[m];
        DOT4(af0, wfx[0][m], vv); DOT4(af1, wfx[1][m], vv);
        DOT4(ag0, wgx[0][m], vv); DOT4(ag1, wgx[1][m], vv);
      }
      const uint4* u4 = (const uint4*)vx16 + (size_t)cs * 3;
      #pragma unroll
      for (int mm = 0; mm < 2; ++mm) {
        const uint4 uu = u4[mm];
        const half2v p0 = __builtin_bit_cast(half2v, uu.x);
        const half2v p1 = __builtin_bit_cast(half2v, uu.y);
        const half2v p2 = __builtin_bit_cast(half2v, uu.z);
        const half2v p3 = __builtin_bit_cast(half2v, uu.w);
        ai0 = DOT2(wix[0][mm * 4 + 0], p0, ai0); ai0 = DOT2(wix[0][mm * 4 + 1], p1, ai0);
        ai0 = DOT2(wix[0][mm * 4 + 2], p2, ai0); ai0 = DOT2(wix[0][mm * 4 + 3], p3, ai0);
        ai1 = DOT2(wix[1][mm * 4 + 0], p0, ai1); ai1 = DOT2(wix[1][mm * 4 + 1], p1, ai1);
        ai1 = DOT2(wix[1][mm * 4 + 2], p2, ai1); ai1 = DOT2(wix[1][mm * 4 + 3], p3, ai1);
        ao0 = DOT2(wox[0][mm * 4 + 0], p0, ao0); ao0 = DOT2(wox[0][mm * 4 + 1], p1, ao0);
        ao0 = DOT2(wox[0][mm * 4 + 2], p2, ao0); ao0 = DOT2(wox[0][mm * 4 + 3], p3, ao0);
        ao1 = DOT2(wox[1][mm * 4 + 0], p0, ao1); ao1 = DOT2(wox[1][mm * 4 + 1], p1, ao1);
        ao1 = DOT2(wox[1][mm * 4 + 2], p2, ao1); ao1 = DOT2(wox[1][mm * 4 + 3], p3, ao1);
      }
    }

    // ---------------- phase B: sibling h (the critical dependency) ----------------
    float hv;
    if (t == 0) {
      hv = 0.f;
    } else {
      const bool own = (tid >= ownlo) && (tid < ownlo + 32);
      const u64* hw = ringOwn + (size_t)((t - 1) & (RING - 1)) * HDIM + tid;
      u64 u = 0; bool ok = own;
      do {
        if (!ok) { u = aloadU(hw); ok = ((unsigned)(u >> 32) == (unsigned)t); }
      } while (!__all(ok));
      hv = own ? hown[tid - ownlo]
               : __builtin_bit_cast(float, (unsigned)(u & 0xffffffffu));
    }
    vh32[i32] = hv;
    {
      const float nb = __shfl_down(hv, 1);
      if (!(tid & 1)) {
        half2v pk; pk.x = (_Float16)hv; pk.y = (_Float16)nb;
        vh16[i16] = __builtin_bit_cast(unsigned, pk);
      }
    }
    __syncthreads();   // B2

    {
      const float4* v4 = (const float4*)vh32 + (size_t)cs * 17;
      #pragma unroll
      for (int m = 0; m < 4; ++m) {
        const float4 vv = v4[m];
        DOT4(af0, wfh[0][m], vv); DOT4(af1, wfh[1][m], vv);
        DOT4(ag0, wgh[0][m], vv); DOT4(ag1, wgh[1][m], vv);
      }
      const uint4* u4 = (const uint4*)vh16 + (size_t)cs * 3;
      #pragma unroll
      for (int mm = 0; mm < 2; ++mm) {
        const uint4 uu = u4[mm];
        const half2v p0 = __builtin_bit_cast(half2v, uu.x);
        const half2v p1 = __builtin_bit_cast(half2v, uu.y);
        const half2v p2 = __builtin_bit_cast(half2v, uu.z);
        const half2v p3 = __builtin_bit_cast(half2v, uu.w);
        ai0 = DOT2(wih2[0][mm * 4 + 0], p0, ai0); ai0 = DOT2(wih2[0][mm * 4 + 1], p1, ai0);
        ai0 = DOT2(wih2[0][mm * 4 + 2], p2, ai0); ai0 = DOT2(wih2[0][mm * 4 + 3], p3, ai0);
        ai1 = DOT2(wih2[1][mm * 4 + 0], p0, ai1); ai1 = DOT2(wih2[1][mm * 4 + 1], p1, ai1);
        ai1 = DOT2(wih2[1][mm * 4 + 2], p2, ai1); ai1 = DOT2(wih2[1][mm * 4 + 3], p3, ai1);
        ao0 = DOT2(woh2[0][mm * 4 + 0], p0, ao0); ao0 = DOT2(woh2[0][mm * 4 + 1], p1, ao0);
        ao0 = DOT2(woh2[0][mm * 4 + 2], p2, ao0); ao0 = DOT2(woh2[0][mm * 4 + 3], p3, ao0);
        ao1 = DOT2(woh2[1][mm * 4 + 0], p0, ao1); ao1 = DOT2(woh2[1][mm * 4 + 1], p1, ao1);
        ao1 = DOT2(woh2[1][mm * 4 + 2], p2, ao1); ao1 = DOT2(woh2[1][mm * 4 + 3], p3, ao1);
      }
    }

    // reduce across the 32 k-chunk lanes (aligned 32-lane groups)
    #pragma unroll
    for (int d = 1; d < 32; d <<= 1) {
      ai0 += __shfl_xor(ai0, d); af0 += __shfl_xor(af0, d);
      ag0 += __shfl_xor(ag0, d); ao0 += __shfl_xor(ao0, d);
      ai1 += __shfl_xor(ai1, d); af1 += __shfl_xor(af1, d);
      ag1 += __shfl_xor(ag1, d); ao1 += __shfl_xor(ao1, d);
    }

    if (cs == 0) {
      const float aiv[2] = {ai0, ai1}, afv[2] = {af0, af1};
      const float agv[2] = {ag0, ag1}, aov[2] = {ao0, ao1};
      #pragma unroll
      for (int j = 0; j < 2; ++j) {
        const float gi = sigm(aiv[j] + bs[j][0]);
        const float gf = sigm(afv[j] + bs[j][1]);
        const float gg = tanhx(agv[j] + bs[j][2]);
        const float go = sigm(aov[j] + bs[j][3]);
        cst[j] = gf * cst[j] + gi * gg;
        const float h = go * tanhx(cst[j]);
        const int hj = ownlo + rq * 2 + j;
        astoreU(ringOwn + (size_t)slot * HDIM + hj,
                ((u64)(unsigned)(t + 1) << 32) | (u64)__builtin_bit_cast(unsigned, h));
        if (layer == NL - 1) a.sout[(size_t)t * HDIM + hj] = h;
        hown[rq * 2 + j] = h;
      }
    }
    if (tid == 0 && (t & 7) == 7)
      __hip_atomic_store(myprog, (unsigned)(t + 1), __ATOMIC_RELAXED,
                         __HIP_MEMORY_SCOPE_AGENT);
  }
}

// ---------------- MLP head: (T,512) -> 64 -> 32 -> 16 ----------------
__global__ void __launch_bounds__(64) mlp_head_kernel(
    const float* __restrict__ S,
    const float* __restrict__ w1, const float* __restrict__ b1,
    const float* __restrict__ w2, const float* __restrict__ b2,
    const float* __restrict__ w3, const float* __restrict__ b3,
    float* __restrict__ out)
{
  const int r   = blockIdx.x;
  const int tid = threadIdx.x;
  __shared__ float hbuf[HDIM];
  __shared__ float a1[64];
  __shared__ float a2[32];

  #pragma unroll
  for (int u = 0; u < HDIM / 64; ++u)
    hbuf[u * 64 + tid] = S[(size_t)r * HDIM + u * 64 + tid];
  __syncthreads();

  float acc = b1[tid];
  #pragma unroll 8
  for (int k = 0; k < HDIM; ++k) acc = fmaf(hbuf[k], w1[tid * HDIM + k], acc);
  a1[tid] = acc * sigm(acc);
  __syncthreads();

  if (tid < 32) {
    float acc2 = b2[tid];
    #pragma unroll
    for (int k = 0; k < 64; ++k) acc2 = fmaf(a1[k], w2[tid * 64 + k], acc2);
    a2[tid] = acc2 * sigm(acc2);
  }
  __syncthreads();

  if (tid < 16) {
    float acc3 = b3[tid];
    #pragma unroll
    for (int k = 0; k < 32; ++k) acc3 = fmaf(a2[k], w3[tid * 32 + k], acc3);
    out[(size_t)r * 16 + tid] = acc3;
  }
}

// ---------------------------------------------------------------------------
extern "C" void kernel_launch(void* const* d_in, const int* in_sizes, int n_in,
                              void* d_out, int out_size, void* d_ws, size_t ws_size,
                              hipStream_t stream)
{
  (void)in_sizes; (void)n_in; (void)out_size; (void)ws_size;

  const float* x     = (const float*)d_in[0];
  const float* eWih0 = (const float*)d_in[1];
  const float* eWhh0 = (const float*)d_in[2];
  const float* ebih0 = (const float*)d_in[3];
  const float* ebhh0 = (const float*)d_in[4];
  const float* eWih  = (const float*)d_in[5];
  const float* eWhh  = (const float*)d_in[6];
  const float* ebih  = (const float*)d_in[7];
  const float* ebhh  = (const float*)d_in[8];
  const float* dWih  = (const float*)d_in[9];
  const float* dWhh  = (const float*)d_in[10];
  const float* dbih  = (const float*)d_in[11];
  const float* dbhh  = (const float*)d_in[12];
  const float* fc1w  = (const float*)d_in[13];
  const float* fc1b  = (const float*)d_in[14];
  const float* fc2w  = (const float*)d_in[15];
  const float* fc2b  = (const float*)d_in[16];
  const float* fc3w  = (const float*)d_in[17];
  const float* fc3b  = (const float*)d_in[18];
  float* out = (float*)d_out;

  // ws layout: ring 4 MB | prog (4 KB pad) | sout 8 MB
  const size_t RINGBYTES = (size_t)NL * RING * HDIM * sizeof(u64);  // 4 MB
  Args p{};
  p.x    = x;
  p.ring = (u64*)d_ws;
  p.prog = (unsigned*)((char*)d_ws + RINGBYTES);
  p.sout = (float*)((char*)d_ws + RINGBYTES + 4096);

  p.Wih[0] = eWih0; p.Whh[0] = eWhh0; p.bih[0] = ebih0; p.bhh[0] = ebhh0;
  for (int l = 1; l < 8; ++l) {
    p.Wih[l] = eWih + (size_t)(l - 1) * 4 * HDIM * HDIM;
    p.Whh[l] = eWhh + (size_t)(l - 1) * 4 * HDIM * HDIM;
    p.bih[l] = ebih + (size_t)(l - 1) * 4 * HDIM;
    p.bhh[l] = ebhh + (size_t)(l - 1) * 4 * HDIM;
  }
  for (int l = 8; l < 16; ++l) {
    p.Wih[l] = dWih + (size_t)(l - 8) * 4 * HDIM * HDIM;
    p.Whh[l] = dWhh + (size_t)(l - 8) * 4 * HDIM * HDIM;
    p.bih[l] = dbih + (size_t)(l - 8) * 4 * HDIM;
    p.bhh[l] = dbhh + (size_t)(l - 8) * 4 * HDIM;
  }

  // clear rings (tags) + progress flags each launch -> replay-safe
  hipMemsetAsync(d_ws, 0, RINGBYTES + 4096, stream);

  void* args[] = { &p };
  hipError_t e = hipLaunchCooperativeKernel((const void*)lstm16_kernel,
                                            dim3(NL * BPL), dim3(NTH), args, 0,
                                            stream);
  if (e != hipSuccess)   // 256 blocks @ 1/CU on 256 CUs: co-resident anyway
    lstm16_kernel<<<dim3(NL * BPL), dim3(NTH), 0, stream>>>(p);

  mlp_head_kernel<<<dim3(T_SEQ), dim3(64), 0, stream>>>(
      p.sout, fc1w, fc1b, fc2w, fc2b, fc3w, fc3b, out);
}

// Round 4
// 9240.846 us; speedup vs baseline: 1.8010x; 1.8010x over previous
//
#include <hip/hip_runtime.h>
#include <math.h>

// ---------------------------------------------------------------------------
// Fused 16-layer LSTM pipeline (H=512, T=4096) + MLP head.
//
//  - 256 blocks = 16 layers x 16 blocks/layer, 1024 thr (16 waves), 1/CU.
//  - Per thread: 1 h-index (hi=tid>>5) x 4 gates x 16-k chunk (cs=tid&31),
//    ALL weights f16-packed in VGPRs: 64 u32 -> total regs ~110 < 128 cap.
//    (Round-3 bug: 192 reg-equivalents vs 128 cap -> per-step global remat,
//    374 GB FETCH. Fitting under the compiler's chosen cap kills it.)
//  - fp32 accumulation via v_dot2_f32_f16.
//  - Steady-state period = h-cycle only: x is a feed-forward edge absorbed
//    by per-layer offsets. Waves 0-7 poll h (critical), waves 8-15 poll x
//    (slack, prefetched one step ahead into parity-double-buffered vx).
//    x-dots execute while the h tagged-load is in flight.
//  - Handshake: tagged {h bits, step} u64 atoms, relaxed agent scope (same
//    protocol as rounds 2/3, visibility proven). Backpressure via every-8
//    progress flags, checked off the critical path.
// ---------------------------------------------------------------------------

#define T_SEQ 4096
#define HDIM  512
#define NL    16
#define BPL   16
#define NTH   1024
#define RING  64

typedef unsigned long long u64;
typedef _Float16 half2v __attribute__((ext_vector_type(2)));

struct Args {
  const float* x;
  const float* Wih[NL]; const float* Whh[NL];
  const float* bih[NL]; const float* bhh[NL];
  u64* ring;        // [NL][RING][HDIM] tagged h
  unsigned* prog;   // [(NL+1)*BPL] progress flags
  float* sout;      // [T_SEQ][HDIM]
};

__device__ __forceinline__ u64 aloadU(const u64* p) {
  return __hip_atomic_load(p, __ATOMIC_RELAXED, __HIP_MEMORY_SCOPE_AGENT);
}
__device__ __forceinline__ void astoreU(u64* p, u64 v) {
  __hip_atomic_store(p, v, __ATOMIC_RELAXED, __HIP_MEMORY_SCOPE_AGENT);
}
__device__ __forceinline__ unsigned aloadu(const unsigned* p) {
  return __hip_atomic_load(p, __ATOMIC_RELAXED, __HIP_MEMORY_SCOPE_AGENT);
}
__device__ __forceinline__ float sigm(float x) { return 1.f / (1.f + __expf(-x)); }
__device__ __forceinline__ float tanhx(float x) {
  const float e = __expf(-2.f * fabsf(x));
  return copysignf((1.f - e) / (1.f + e), x);
}

#if __has_builtin(__builtin_amdgcn_fdot2)
#define DOT2(w, v, acc) __builtin_amdgcn_fdot2((w), (v), (acc), false)
#else
__device__ __forceinline__ float DOT2(half2v w, half2v v, float acc) {
  return acc + (float)w.x * (float)v.x + (float)w.y * (float)v.y;
}
#endif

#define BC(u) __builtin_bit_cast(half2v, (u))
#define DOTS8(acc, W) \
  acc = DOT2(W[0], p0, acc); acc = DOT2(W[1], p1, acc); \
  acc = DOT2(W[2], p2, acc); acc = DOT2(W[3], p3, acc); \
  acc = DOT2(W[4], p4, acc); acc = DOT2(W[5], p5, acc); \
  acc = DOT2(W[6], p6, acc); acc = DOT2(W[7], p7, acc)

__global__ void __launch_bounds__(NTH) lstm16_kernel(Args a)
{
  const int tid   = threadIdx.x;
  const int layer = blockIdx.x & 15;   // layer l -> XCD l&7 (blockIdx%8)
  const int b     = blockIdx.x >> 4;
  const int hi    = tid >> 5;          // 0..31: h-index within block
  const int cs    = tid & 31;          // 0..31: k-chunk (16 floats x + 16 h)
  const int kx    = cs * 16;
  const int hq    = b * 32 + hi;       // global h row 0..511
  const int D     = layer ? HDIM : 128;

  // ---- weights: all 4 gates f16-packed, 64 VGPRs total ----
  half2v wx[4][8], wh[4][8];
  float  bs[4];
  const bool xok = (kx + 16 <= D);
  #pragma unroll
  for (int q = 0; q < 4; ++q) {
    const int row = q * HDIM + hq;
    bs[q] = a.bih[layer][row] + a.bhh[layer][row];
    const float2* px = (const float2*)(a.Wih[layer] + (size_t)row * D + kx);
    const float2* ph = (const float2*)(a.Whh[layer] + (size_t)row * HDIM + kx);
    #pragma unroll
    for (int p = 0; p < 8; ++p) {
      const float2 t0 = xok ? px[p] : make_float2(0.f, 0.f);
      const float2 t1 = ph[p];
      half2v w0; w0.x = (_Float16)t0.x; w0.y = (_Float16)t0.y; wx[q][p] = w0;
      half2v w1; w1.x = (_Float16)t1.x; w1.y = (_Float16)t1.y; wh[q][p] = w1;
    }
  }

  // LDS: x parity-double-buffered, h single (stride 10 u32 -> 2-way = free)
  __shared__ __align__(8) unsigned vx16[2][320];
  __shared__ __align__(8) unsigned vh16[320];

  u64* ringOwn        = a.ring + (size_t)layer * RING * HDIM;
  const u64* ringPrev = a.ring + (size_t)(layer ? layer - 1 : 0) * RING * HDIM;
  const unsigned* progNext = a.prog + (layer + 1) * BPL;
  unsigned* myprog         = a.prog + layer * BPL + b;

  // ---- x staging for step tt into vx16[tt&1] (waves 8-15 only) ----
  auto stage_x = [&](int tt) {
    if (tid < 512) return;
    const int w = tid - 512;
    bool okbp = !((layer < NL - 1) && (w < 16) && ((tt & 7) == 0));
    float xv = 0.f;
    if (layer == 0) {
      if (w < 128) xv = a.x[(size_t)tt * 128 + w];
      if (!okbp)
        while ((int)aloadu(progNext + w) < tt - 40) __builtin_amdgcn_s_sleep(2);
    } else {
      const u64* xw = ringPrev + (size_t)(tt & (RING - 1)) * HDIM + w;
      u64 u = aloadU(xw);
      bool ok = ((unsigned)(u >> 32) == (unsigned)(tt + 1));
      while (!__all(ok & okbp)) {
        if (!ok) {
          u = aloadU(xw);
          ok = ((unsigned)(u >> 32) == (unsigned)(tt + 1));
          if (!ok) __builtin_amdgcn_s_sleep(1);
        }
        if (!okbp) okbp = ((int)aloadu(progNext + w) >= tt - 40);
      }
      xv = __builtin_bit_cast(float, (unsigned)(u & 0xffffffffu));
    }
    const float nb = __shfl_down(xv, 1);
    if (!(w & 1)) {
      half2v pk; pk.x = (_Float16)xv; pk.y = (_Float16)nb;
      vx16[tt & 1][(w >> 4) * 10 + ((w & 15) >> 1)] =
          __builtin_bit_cast(unsigned, pk);
    }
  };

  stage_x(0);
  __syncthreads();

  float c_state = 0.f;   // lanes cs==0 own h-index hq

  for (int t = 0; t < T_SEQ; ++t) {
    // ---- issue h tagged-load early (hides under x-dots) ----
    u64 hu = 0; const u64* hw = ringOwn;
    const bool hpoll = (t > 0) && (tid < 512);
    if (hpoll) {
      hw = ringOwn + (size_t)((t - 1) & (RING - 1)) * HDIM + tid;
      hu = aloadU(hw);
    }

    // ---- x-dots from vx16[t&1] (staged last iteration) ----
    float a0 = 0.f, a1 = 0.f, a2 = 0.f, a3 = 0.f;
    {
      const unsigned* vb = vx16[t & 1] + cs * 10;
      const uint2 u0 = *(const uint2*)(vb + 0);
      const uint2 u1 = *(const uint2*)(vb + 2);
      const uint2 u2 = *(const uint2*)(vb + 4);
      const uint2 u3 = *(const uint2*)(vb + 6);
      const half2v p0 = BC(u0.x), p1 = BC(u0.y), p2 = BC(u1.x), p3 = BC(u1.y);
      const half2v p4 = BC(u2.x), p5 = BC(u2.y), p6 = BC(u3.x), p7 = BC(u3.y);
      DOTS8(a0, wx[0]); DOTS8(a1, wx[1]); DOTS8(a2, wx[2]); DOTS8(a3, wx[3]);
    }

    // ---- h: finish poll, stage, dots ----
    if (t > 0) {
      if (tid < 512) {
        bool ok = ((unsigned)(hu >> 32) == (unsigned)t);
        while (!__all(ok)) {
          if (!ok) { hu = aloadU(hw); ok = ((unsigned)(hu >> 32) == (unsigned)t); }
        }
        const float hv = __builtin_bit_cast(float, (unsigned)(hu & 0xffffffffu));
        const float nb = __shfl_down(hv, 1);
        if (!(tid & 1)) {
          half2v pk; pk.x = (_Float16)hv; pk.y = (_Float16)nb;
          vh16[(tid >> 4) * 10 + ((tid & 15) >> 1)] =
              __builtin_bit_cast(unsigned, pk);
        }
      }
      __syncthreads();   // BAR1: vh staged
      {
        const unsigned* vb = vh16 + cs * 10;
        const uint2 u0 = *(const uint2*)(vb + 0);
        const uint2 u1 = *(const uint2*)(vb + 2);
        const uint2 u2 = *(const uint2*)(vb + 4);
        const uint2 u3 = *(const uint2*)(vb + 6);
        const half2v p0 = BC(u0.x), p1 = BC(u0.y), p2 = BC(u1.x), p3 = BC(u1.y);
        const half2v p4 = BC(u2.x), p5 = BC(u2.y), p6 = BC(u3.x), p7 = BC(u3.y);
        DOTS8(a0, wh[0]); DOTS8(a1, wh[1]); DOTS8(a2, wh[2]); DOTS8(a3, wh[3]);
      }
    }

    // ---- reduce across 32 k-lanes (stays within 32-lane halves) ----
    #pragma unroll
    for (int d = 1; d < 32; d <<= 1) {
      a0 += __shfl_xor(a0, d); a1 += __shfl_xor(a1, d);
      a2 += __shfl_xor(a2, d); a3 += __shfl_xor(a3, d);
    }

    // ---- gates + post (lanes cs==0: one per h-index) ----
    if (cs == 0) {
      const float gi = sigm(a0 + bs[0]);
      const float gf = sigm(a1 + bs[1]);
      const float gg = tanhx(a2 + bs[2]);
      const float go = sigm(a3 + bs[3]);
      c_state = gf * c_state + gi * gg;
      const float h = go * tanhx(c_state);
      astoreU(ringOwn + (size_t)(t & (RING - 1)) * HDIM + hq,
              ((u64)(unsigned)(t + 1) << 32) | (u64)__builtin_bit_cast(unsigned, h));
      if (layer == NL - 1) a.sout[(size_t)t * HDIM + hq] = h;
    }
    if (tid == 0 && (t & 7) == 7)
      __hip_atomic_store(myprog, (unsigned)(t + 1), __ATOMIC_RELAXED,
                         __HIP_MEMORY_SCOPE_AGENT);

    // ---- prefetch x_{t+1} (slack path, waves 8-15) ----
    if (t + 1 < T_SEQ) stage_x(t + 1);
    __syncthreads();     // BAR2
  }
}

// ---------------- MLP head: (T,512) -> 64 -> 32 -> 16 ----------------
__global__ void __launch_bounds__(64) mlp_head_kernel(
    const float* __restrict__ S,
    const float* __restrict__ w1, const float* __restrict__ b1,
    const float* __restrict__ w2, const float* __restrict__ b2,
    const float* __restrict__ w3, const float* __restrict__ b3,
    float* __restrict__ out)
{
  const int r   = blockIdx.x;
  const int tid = threadIdx.x;
  __shared__ __align__(16) float hbuf[HDIM];
  __shared__ float a1[64];
  __shared__ float a2[32];

  #pragma unroll
  for (int u = 0; u < HDIM / 64; ++u)
    hbuf[u * 64 + tid] = S[(size_t)r * HDIM + u * 64 + tid];
  __syncthreads();

  float acc = b1[tid];
  {
    const float4* w4 = (const float4*)(w1 + (size_t)tid * HDIM);
    const float4* h4 = (const float4*)hbuf;
    #pragma unroll 8
    for (int k = 0; k < HDIM / 4; ++k) {
      const float4 wv = w4[k], hv = h4[k];
      acc = fmaf(wv.x, hv.x, acc); acc = fmaf(wv.y, hv.y, acc);
      acc = fmaf(wv.z, hv.z, acc); acc = fmaf(wv.w, hv.w, acc);
    }
  }
  a1[tid] = acc * sigm(acc);
  __syncthreads();

  if (tid < 32) {
    float acc2 = b2[tid];
    #pragma unroll
    for (int k = 0; k < 64; ++k) acc2 = fmaf(a1[k], w2[tid * 64 + k], acc2);
    a2[tid] = acc2 * sigm(acc2);
  }
  __syncthreads();

  if (tid < 16) {
    float acc3 = b3[tid];
    #pragma unroll
    for (int k = 0; k < 32; ++k) acc3 = fmaf(a2[k], w3[tid * 32 + k], acc3);
    out[(size_t)r * 16 + tid] = acc3;
  }
}

// ---------------------------------------------------------------------------
extern "C" void kernel_launch(void* const* d_in, const int* in_sizes, int n_in,
                              void* d_out, int out_size, void* d_ws, size_t ws_size,
                              hipStream_t stream)
{
  (void)in_sizes; (void)n_in; (void)out_size; (void)ws_size;

  const float* x     = (const float*)d_in[0];
  const float* eWih0 = (const float*)d_in[1];
  const float* eWhh0 = (const float*)d_in[2];
  const float* ebih0 = (const float*)d_in[3];
  const float* ebhh0 = (const float*)d_in[4];
  const float* eWih  = (const float*)d_in[5];
  const float* eWhh  = (const float*)d_in[6];
  const float* ebih  = (const float*)d_in[7];
  const float* ebhh  = (const float*)d_in[8];
  const float* dWih  = (const float*)d_in[9];
  const float* dWhh  = (const float*)d_in[10];
  const float* dbih  = (const float*)d_in[11];
  const float* dbhh  = (const float*)d_in[12];
  const float* fc1w  = (const float*)d_in[13];
  const float* fc1b  = (const float*)d_in[14];
  const float* fc2w  = (const float*)d_in[15];
  const float* fc2b  = (const float*)d_in[16];
  const float* fc3w  = (const float*)d_in[17];
  const float* fc3b  = (const float*)d_in[18];
  float* out = (float*)d_out;

  // ws layout: ring 4 MB | prog (4 KB) | sout 8 MB
  const size_t RINGBYTES = (size_t)NL * RING * HDIM * sizeof(u64);  // 4 MB
  Args p{};
  p.x    = x;
  p.ring = (u64*)d_ws;
  p.prog = (unsigned*)((char*)d_ws + RINGBYTES);
  p.sout = (float*)((char*)d_ws + RINGBYTES + 4096);

  p.Wih[0] = eWih0; p.Whh[0] = eWhh0; p.bih[0] = ebih0; p.bhh[0] = ebhh0;
  for (int l = 1; l < 8; ++l) {
    p.Wih[l] = eWih + (size_t)(l - 1) * 4 * HDIM * HDIM;
    p.Whh[l] = eWhh + (size_t)(l - 1) * 4 * HDIM * HDIM;
    p.bih[l] = ebih + (size_t)(l - 1) * 4 * HDIM;
    p.bhh[l] = ebhh + (size_t)(l - 1) * 4 * HDIM;
  }
  for (int l = 8; l < 16; ++l) {
    p.Wih[l] = dWih + (size_t)(l - 8) * 4 * HDIM * HDIM;
    p.Whh[l] = dWhh + (size_t)(l - 8) * 4 * HDIM * HDIM;
    p.bih[l] = dbih + (size_t)(l - 8) * 4 * HDIM;
    p.bhh[l] = dbhh + (size_t)(l - 8) * 4 * HDIM;
  }

  // clear rings (tags) + progress flags each launch -> replay-safe
  hipMemsetAsync(d_ws, 0, RINGBYTES + 4096, stream);

  void* args[] = { &p };
  hipError_t e = hipLaunchCooperativeKernel((const void*)lstm16_kernel,
                                            dim3(NL * BPL), dim3(NTH), args, 0,
                                            stream);
  if (e != hipSuccess)   // 256 blocks @ 1/CU on 256 CUs: co-resident anyway
    lstm16_kernel<<<dim3(NL * BPL), dim3(NTH), 0, stream>>>(p);

  mlp_head_kernel<<<dim3(T_SEQ), dim3(64), 0, stream>>>(
      p.sout, fc1w, fc1b, fc2w, fc2b, fc3w, fc3b, out);
}